// Round 7
// baseline (261.639 us; speedup 1.0000x reference)
//
#include <hip/hip_runtime.h>
#include <hip/hip_bf16.h>

typedef unsigned short u16;
typedef unsigned int u32;
typedef __attribute__((ext_vector_type(8))) __bf16 bf16x8;
typedef __attribute__((ext_vector_type(4))) __bf16 bf16x4;
typedef __attribute__((ext_vector_type(4))) float f32x4;

#define KCTX 32
#define INF_ 608
#define HID_ 384
#define NBOX 16384

// ws layout (bytes).
#define AW_OFF  0                     // aw  [16384][32] float2 = 4,194,304
#define CNT_OFF 4194304               // cnt [16384] i32        =    65,536
#define WRK_OFF 4259840               // wrk [8] i32 work counters
#define WH_OFF  19922944              // Wh2 [8][16384][48] bf16 = 12,582,912 (slice-major)
#define BT_OFF  32505856              // Bt  [384,608]  bf16 =    466,944
#define V_OFF   32972800              // v   [608] f32        =      2,432
#define SI_OFF  32975232              // si  [16384] f32      =     65,536
#define SJ_OFF  33040768              // sj  [16384] f32      =     65,536
#define AJF_OFF 33106304              // ajf [384] f32        =      1,536
#define ABF_OFF 33107840              // abf [1] f32

__device__ __forceinline__ float bfu(u16 u)  { return __uint_as_float(((u32)u) << 16); }
__device__ __forceinline__ float bflo(u32 u) { return __uint_as_float(u << 16); }
__device__ __forceinline__ float bfhi(u32 u) { return __uint_as_float(u & 0xffff0000u); }
__device__ __forceinline__ u16 f2bf(float x) {            // round-to-nearest-even
  u32 u = __float_as_uint(x);
  return (u16)((u + 0x7fffu + ((u >> 16) & 1u)) >> 16);
}
__device__ __forceinline__ void async_ld16(const void* g, void* l) {
  __builtin_amdgcn_global_load_lds(
      (const __attribute__((address_space(1))) u32*)g,
      (__attribute__((address_space(3))) u32*)l, 16, 0, 0);
}

// ---- per-wave runtime dtype detection (wave-uniform, L2-hot; validated r2-r8) ----
__device__ __forceinline__ int detect_f32(const u32* hw) {
  const u32 w = hw[threadIdx.x & 63];
  const int e = (int)((w >> 7) & 0xffu);
  const unsigned long long mb = __ballot(e > 134 || e < 100);
  return __popcll(mb) >= 16;
}
__device__ __forceinline__ int detect_i64(const int* ci) {
  const int hi = ci[2 * (threadIdx.x & 63) + 1];
  const unsigned long long mz = __ballot(hi == 0 || hi == -1);
  return __popcll(mz) >= 48;
}

// ---- prep: Bt = bf16(W_j^T), v = W_i@a_i, ajf/abf fp32 (r4 version) ----
__global__ __launch_bounds__(256) void prep_kernel(
    const void* __restrict__ h, const void* __restrict__ Wi,
    const void* __restrict__ Wj, const void* __restrict__ ai,
    const void* __restrict__ aj, const void* __restrict__ ab,
    u16* __restrict__ Bt, float* __restrict__ v,
    float* __restrict__ ajf, float* __restrict__ abf) {
  __shared__ u16 tile[64][65];
  const int f32m = detect_f32((const u32*)h);
  const int bid = blockIdx.x, tid = threadIdx.x;
  if (bid < 60) {                                  // transpose: 10(f) x 6(h) tiles
    const int ft = bid / 6, ht = bid - ft * 6;
    const int f0 = ft * 64, h0 = ht * 64;
    const int ln = tid & 63, fg = tid >> 6;
#pragma unroll
    for (int rr = 0; rr < 16; ++rr) {
      const int fl = fg * 16 + rr;
      const int f = f0 + fl;
      if (f < INF_)
        tile[fl][ln] = f32m ? f2bf(((const float*)Wj)[(size_t)f * HID_ + h0 + ln])
                            : ((const u16*)Wj)[(size_t)f * HID_ + h0 + ln];
    }
    __syncthreads();
#pragma unroll
    for (int rr = 0; rr < 16; ++rr) {
      const int hl = fg * 16 + rr;
      const int f = f0 + ln;
      if (f < INF_) Bt[(size_t)(h0 + hl) * INF_ + f] = tile[ln][hl];
    }
  } else if (bid < 98) {                           // v: 16-lane group per row
    const int t = (bid - 60) * 16 + (tid >> 4);
    const int sl = tid & 15;
    if (t < INF_) {
      float s = 0.f;
      if (f32m) {
        const float4* wi = (const float4*)((const float*)Wi + (size_t)t * HID_);
        const float4* a4 = (const float4*)ai;
        for (int c = sl; c < 96; c += 16) {
          float4 x = wi[c], y = a4[c];
          s += x.x * y.x + x.y * y.y + x.z * y.z + x.w * y.w;
        }
      } else {
        const uint4* wi = (const uint4*)((const u16*)Wi + (size_t)t * HID_);
        const uint4* a4 = (const uint4*)ai;
        for (int c = sl; c < 48; c += 16) {
          uint4 x = wi[c], y = a4[c];
          s += bflo(x.x) * bflo(y.x) + bfhi(x.x) * bfhi(y.x)
             + bflo(x.y) * bflo(y.y) + bfhi(x.y) * bfhi(y.y)
             + bflo(x.z) * bflo(y.z) + bfhi(x.z) * bfhi(y.z)
             + bflo(x.w) * bflo(y.w) + bfhi(x.w) * bfhi(y.w);
        }
      }
      s += __shfl_xor(s, 1); s += __shfl_xor(s, 2);
      s += __shfl_xor(s, 4); s += __shfl_xor(s, 8);
      if (sl == 0) v[t] = s;
    }
  } else {                                         // ajf/abf only
    for (int j = tid; j < HID_; j += 256)
      ajf[j] = f32m ? ((const float*)aj)[j] : bfu(((const u16*)aj)[j]);
    if (tid == 0)
      abf[0] = f32m ? ((const float*)ab)[0] : bfu(((const u16*)ab)[0]);
  }
}

// ---- gemm_fused (r4 version, known 43.5us; slice-major C write) ----
#define ASRO 612
__global__ __launch_bounds__(512, 2) void gemm_fused(
    const void* __restrict__ A, const u16* __restrict__ Bt,
    const float* __restrict__ v, u16* __restrict__ C,
    float* __restrict__ si, const float* __restrict__ ajf,
    float* __restrict__ sj) {
  extern __shared__ __align__(16) char smem[];
  u16* As = (u16*)smem;                            // [64][612]
  u16* Bs = (u16*)(smem + 78336);                  // [2][384][32]
  const int f32m = detect_f32((const u32*)A);
  const int tid  = threadIdx.x;
  const int lane = tid & 63;
  const int wv   = tid >> 6;                       // 0..7
  const int row0 = blockIdx.x * 64;
  const char* Btb = (const char*)Bt;

#pragma unroll
  for (int i = 0; i < 3; ++i) {
    const int c = tid + i * 512;                   // 1536 x 16B = 24576 B
    async_ld16(Btb + (size_t)(c >> 2) * 1216 + (c & 3) * 16, (char*)Bs + c * 16);
  }

  {                                                // As fill + si, 8 thr/row
    const int g = tid >> 3, sub = tid & 7;         // g 0..63
    float s = 0.f;
    const float4* v4 = (const float4*)v;
    if (f32m) {
      const float4* hr = (const float4*)((const float*)A + (size_t)(row0 + g) * INF_);
#pragma unroll
      for (int k = 0; k < 19; ++k) {
        const int c4 = sub + 8 * k;
        float4 x = hr[c4];
        ushort4 sv;
        sv.x = f2bf(x.x); sv.y = f2bf(x.y); sv.z = f2bf(x.z); sv.w = f2bf(x.w);
        *(ushort4*)&As[g * ASRO + c4 * 4] = sv;
        float4 w = v4[c4];
        s += x.x * w.x + x.y * w.y + x.z * w.z + x.w * w.w;
      }
    } else {
      const uint4* hr = (const uint4*)((const u16*)A + (size_t)(row0 + g) * INF_);
      for (int k = 0; k < 10; ++k) {
        const int c8 = sub + 8 * k;
        if (c8 < 76) {
          uint4 x = hr[c8];
          *(ushort4*)&As[g * ASRO + c8 * 8]     = *(ushort4*)&x.x;
          *(ushort4*)&As[g * ASRO + c8 * 8 + 4] = *(ushort4*)&x.z;
          float4 w0 = v4[2 * c8], w1 = v4[2 * c8 + 1];
          s += bflo(x.x) * w0.x + bfhi(x.x) * w0.y + bflo(x.y) * w0.z + bfhi(x.y) * w0.w
             + bflo(x.z) * w1.x + bfhi(x.z) * w1.y + bflo(x.w) * w1.z + bfhi(x.w) * w1.w;
        }
      }
    }
    s += __shfl_xor(s, 1); s += __shfl_xor(s, 2); s += __shfl_xor(s, 4);
    if (sub == 0) si[row0 + g] = s;
  }

  f32x4 acc[4][3];
#pragma unroll
  for (int i = 0; i < 4; ++i)
#pragma unroll
    for (int j = 0; j < 3; ++j) acc[i][j] = (f32x4){0.f, 0.f, 0.f, 0.f};

  const int lm = lane & 15, q = lane >> 4;
  const int n0 = wv * 48;                          // 8 waves x 48 cols = 384

  __syncthreads();                                 // Bs[0] + As ready
  int cur = 0;
  for (int kt = 0; kt < 19; ++kt) {
    if (kt < 18) {                                 // stage kt+1 into buf^1 FIRST
      const size_t kb = (size_t)(kt + 1) * 64;
#pragma unroll
      for (int i = 0; i < 3; ++i) {
        const int c = tid + i * 512;
        async_ld16(Btb + (size_t)(c >> 2) * 1216 + kb + (c & 3) * 16,
                   (char*)Bs + (cur ^ 1) * 24576 + c * 16);
      }
    }
    bf16x8 af[4], bfr[3];
#pragma unroll
    for (int im = 0; im < 4; ++im) {
      const int r = im * 16 + lm;
      bf16x4 lo = *(const bf16x4*)&As[r * ASRO + kt * 32 + q * 8];
      bf16x4 hi = *(const bf16x4*)&As[r * ASRO + kt * 32 + q * 8 + 4];
      af[im] = __builtin_shufflevector(lo, hi, 0, 1, 2, 3, 4, 5, 6, 7);
    }
#pragma unroll
    for (int in = 0; in < 3; ++in)
      bfr[in] = *(const bf16x8*)&Bs[cur * 12288 + (n0 + in * 16 + lm) * 32 + q * 8];
#pragma unroll
    for (int im = 0; im < 4; ++im)
#pragma unroll
      for (int in = 0; in < 3; ++in)
        acc[im][in] = __builtin_amdgcn_mfma_f32_16x16x32_bf16(
            af[im], bfr[in], acc[im][in], 0, 0, 0);
    __syncthreads();                               // drains vmcnt -> buf^1 ready
    cur ^= 1;
  }

#pragma unroll
  for (int im = 0; im < 4; ++im)
#pragma unroll
    for (int in = 0; in < 3; ++in) {
      const int cw = in * 16 + lm;                 // col within slice wv
#pragma unroll
      for (int r = 0; r < 4; ++r) {
        const int rowg = row0 + im * 16 + q * 4 + r;
        C[((size_t)wv * NBOX + rowg) * 48 + cw] = f2bf(acc[im][in][r]);
      }
    }
  float* sjred = (float*)Bs;                       // [8][64] f32 = 2 KB
  float ajv[3];
#pragma unroll
  for (int in = 0; in < 3; ++in) ajv[in] = ajf[n0 + in * 16 + lm];
#pragma unroll
  for (int im = 0; im < 4; ++im)
#pragma unroll
    for (int r = 0; r < 4; ++r) {
      float p = acc[im][0][r] * ajv[0] + acc[im][1][r] * ajv[1]
              + acc[im][2][r] * ajv[2];
      p += __shfl_xor(p, 1); p += __shfl_xor(p, 2);
      p += __shfl_xor(p, 4); p += __shfl_xor(p, 8);
      if (lm == 0) sjred[wv * 64 + im * 16 + q * 4 + r] = p;
    }
  __syncthreads();
  if (tid < 64) {
    float s = 0.f;
#pragma unroll
    for (int w = 0; w < 8; ++w) s += sjred[w * 64 + tid];
    sj[row0 + tid] = s;
  }
}

// ---- score: softmax weights once per row, compacted (ballot prefix),
// padded to multiple of 4; also zeroes the gather work counters. ----
__global__ __launch_bounds__(256) void score_kernel(
    const int* __restrict__ ci, const float* __restrict__ si,
    const float* __restrict__ sj, const float* __restrict__ abf,
    float2* __restrict__ aw, int* __restrict__ cnt, int* __restrict__ wrk) {
  const int i64 = detect_i64(ci);
  const int tid = threadIdx.x;
  if (blockIdx.x == 0 && tid < 8) wrk[tid] = 0;    // visible at kernel boundary
  const int k = tid & 31;
  const int n = blockIdx.x * 8 + (tid >> 5);       // 2048*8 = 16384 exactly
  const size_t t = (size_t)n * KCTX + k;
  int idx;
  if (i64) { int lo = ci[2 * t], hi2 = ci[2 * t + 1]; idx = (hi2 < 0) ? -1 : lo; }
  else     { idx = ci[t]; }
  const bool valid = idx >= 0;
  const float sjv = valid ? sj[idx] : 0.f;
  float raw = si[n] + sjv + abf[0];
  float lr = raw > 0.f ? raw : 0.2f * raw;
  float s = valid ? lr : -9e15f;
  float m = s;
#pragma unroll
  for (int o = 16; o; o >>= 1) m = fmaxf(m, __shfl_xor(m, o, 32));
  float p = __expf(s - m);
  float d = p;
#pragma unroll
  for (int o = 16; o; o >>= 1) d += __shfl_xor(d, o, 32);
  const float w = p / d;                           // invalid: p==0 => w==0
  const unsigned long long bm = __ballot(valid);
  const u32 m32 = (u32)(bm >> (tid & 32));         // this 32-group's mask
  const int c_ = __popc(m32);
  const int r4 = (c_ + 3) & ~3;                    // pad to multiple of 4
  if (valid) {
    const int pf = __popc(m32 & ((1u << k) - 1u));
    aw[(size_t)n * KCTX + pf] = (float2){w, __int_as_float(idx)};
  }
  if (k >= c_ && k < r4) aw[(size_t)n * KCTX + k] = (float2){0.f, 0.f};
  if (k == 0) cnt[n] = r4;
}

// ---- gather v2: RUNTIME-XCD slice ownership. r4's blockIdx%8->XCD guess
// failed (gather stayed 43.5us = 7.4 TB/s = LLC-fabric ceiling). Now each
// block reads its REAL XCD via s_getreg(HW_REG_XCC_ID) [HW-verified, m09]
// and dynamically claims 64-row chunks from per-slice atomic counters,
// processing ONLY slice x: each XCD streams its private 1.57 MB slice
// (L2-resident) for all rows -> 41 MB/XCD at per-XCD L2 BW, no fabric.
// Work-stealing over the 8 counters guarantees completion for any XCD-id
// distribution (degrades to r4 behavior, never breaks). ----
__global__ __launch_bounds__(384) void gather_kernel(
    const void* __restrict__ h, const float2* __restrict__ aw,
    const int* __restrict__ cnt, const u16* __restrict__ Wh2,
    void* __restrict__ out, int* __restrict__ wrk) {
  __shared__ float2 aws[64 * 33];                  // 16.9 KB
  __shared__ int cs[64];
  __shared__ int chsh;
  const int f32m = detect_f32((const u32*)h);
  const int tid = threadIdx.x;
  u32 xcc;
  asm volatile("s_getreg_b32 %0, hwreg(HW_REG_XCC_ID)" : "=s"(xcc));
  const int myx = (int)(xcc & 7u);
  const int r = tid / 6, c = tid - r * 6;          // r<64, c<6 (384 = 64*6)

#pragma unroll 1
  for (int off = 0; off < 8; ++off) {
    const int s = (myx + off) & 7;                 // own slice first, then steal
    const u16* bc = Wh2 + (size_t)s * NBOX * 48 + c * 8;
#pragma unroll 1
    for (;;) {
      __syncthreads();                             // prev gather done; aws free
      if (tid == 0) chsh = atomicAdd(&wrk[s], 1);
      __syncthreads();
      const int ch = chsh;
      if (ch >= 256) break;
      const int g0 = ch * 64;
      const float2* awg = aw + (size_t)g0 * KCTX;
      for (int i = tid; i < 2048; i += 384) aws[(i >> 5) * 33 + (i & 31)] = awg[i];
      if (tid < 64) cs[tid] = cnt[g0 + tid];
      __syncthreads();

      const int n = g0 + r;
      const int kc = cs[r];
      float a0 = 0, a1 = 0, a2 = 0, a3 = 0, a4 = 0, a5 = 0, a6 = 0, a7 = 0;
      for (int k = 0; k < kc; k += 4) {
        uint4 q[4]; float w4[4];
#pragma unroll
        for (int u = 0; u < 4; ++u) {              // 4 loads in flight
          const float2 e = aws[r * 33 + k + u];
          w4[u] = e.x;
          q[u] = *(const uint4*)(bc + (size_t)((u32)__float_as_int(e.y)) * 48);
        }
#pragma unroll
        for (int u = 0; u < 4; ++u) {
          const float w = w4[u];
          a0 += w * bflo(q[u].x); a1 += w * bfhi(q[u].x);
          a2 += w * bflo(q[u].y); a3 += w * bfhi(q[u].y);
          a4 += w * bflo(q[u].z); a5 += w * bfhi(q[u].z);
          a6 += w * bflo(q[u].w); a7 += w * bfhi(q[u].w);
        }
      }
      if (f32m) {
        float4* o4 = (float4*)((float*)out + (size_t)n * HID_ + s * 48 + c * 8);
        o4[0] = (float4){a0, a1, a2, a3};
        o4[1] = (float4){a4, a5, a6, a7};
      } else {
        uint4 o;
        o.x = (u32)f2bf(a0) | ((u32)f2bf(a1) << 16);
        o.y = (u32)f2bf(a2) | ((u32)f2bf(a3) << 16);
        o.z = (u32)f2bf(a4) | ((u32)f2bf(a5) << 16);
        o.w = (u32)f2bf(a6) | ((u32)f2bf(a7) << 16);
        *(uint4*)((u16*)out + (size_t)n * HID_ + s * 48 + c * 8) = o;
      }
    }
  }
}

extern "C" void kernel_launch(void* const* d_in, const int* in_sizes, int n_in,
                              void* d_out, int out_size, void* d_ws, size_t ws_size,
                              hipStream_t stream) {
  const void* h  = d_in[0];
  const int*  ci = (const int*)d_in[1];
  const void* Wi = d_in[2];
  const void* Wj = d_in[3];
  const void* ai = d_in[4];
  const void* aj = d_in[5];
  const void* ab = d_in[6];

  char* ws = (char*)d_ws;
  float2* aw  = (float2*)(ws + AW_OFF);
  int*    cnt = (int*)(ws + CNT_OFF);
  int*    wrk = (int*)(ws + WRK_OFF);
  u16*   Wh  = (u16*)(ws + WH_OFF);
  u16*   Bt  = (u16*)(ws + BT_OFF);
  float* v   = (float*)(ws + V_OFF);
  float* si  = (float*)(ws + SI_OFF);
  float* sj  = (float*)(ws + SJ_OFF);
  float* ajf = (float*)(ws + AJF_OFF);
  float* abf = (float*)(ws + ABF_OFF);

  prep_kernel<<<99, 256, 0, stream>>>(h, Wi, Wj, ai, aj, ab, Bt, v, ajf, abf);
  gemm_fused<<<256, 512, 127488, stream>>>(h, Bt, v, Wh, si, ajf, sj);
  score_kernel<<<2048, 256, 0, stream>>>(ci, si, sj, abf, aw, cnt, wrk);
  gather_kernel<<<1024, 384, 0, stream>>>(h, aw, cnt, Wh, d_out, wrk);
}

// Round 8
// 157.065 us; speedup vs baseline: 1.6658x; 1.6658x over previous
//
#include <hip/hip_runtime.h>
#include <hip/hip_bf16.h>

typedef unsigned short u16;
typedef unsigned int u32;
typedef __attribute__((ext_vector_type(8))) __bf16 bf16x8;
typedef __attribute__((ext_vector_type(4))) __bf16 bf16x4;
typedef __attribute__((ext_vector_type(4))) float f32x4;

#define KCTX 32
#define INF_ 608
#define HID_ 384
#define NBOX 16384

// ws layout (bytes).
#define WH_OFF  19922944              // Wh  [16384,384] bf16 = 12,582,912
#define BT_OFF  32505856              // Bt  [384,608]  bf16 =    466,944
#define V_OFF   32972800              // v   [608] f32        =      2,432
#define SI_OFF  32975232              // si  [16384] f32      =     65,536
#define SJ_OFF  33040768              // sj  [16384] f32      =     65,536
#define AJF_OFF 33106304              // ajf [384] f32        =      1,536
#define ABF_OFF 33107840              // abf [1] f32

__device__ __forceinline__ float bfu(u16 u)  { return __uint_as_float(((u32)u) << 16); }
__device__ __forceinline__ float bflo(u32 u) { return __uint_as_float(u << 16); }
__device__ __forceinline__ float bfhi(u32 u) { return __uint_as_float(u & 0xffff0000u); }
__device__ __forceinline__ u16 f2bf(float x) {            // round-to-nearest-even
  u32 u = __float_as_uint(x);
  return (u16)((u + 0x7fffu + ((u >> 16) & 1u)) >> 16);
}
__device__ __forceinline__ void async_ld16(const void* g, void* l) {
  __builtin_amdgcn_global_load_lds(
      (const __attribute__((address_space(1))) u32*)g,
      (__attribute__((address_space(3))) u32*)l, 16, 0, 0);
}

// ---- per-wave runtime dtype detection (wave-uniform, L2-hot; validated r2-r8) ----
__device__ __forceinline__ int detect_f32(const u32* hw) {
  const u32 w = hw[threadIdx.x & 63];
  const int e = (int)((w >> 7) & 0xffu);
  const unsigned long long mb = __ballot(e > 134 || e < 100);
  return __popcll(mb) >= 16;
}
__device__ __forceinline__ int detect_i64(const int* ci) {
  const int hi = ci[2 * (threadIdx.x & 63) + 1];
  const unsigned long long mz = __ballot(hi == 0 || hi == -1);
  return __popcll(mz) >= 48;
}

// ---- prep: Bt = bf16(W_j^T), v = W_i@a_i, ajf/abf fp32 (sj-zero removed:
// gemm stores sj directly via LDS reduce, r1-validated) ----
__global__ __launch_bounds__(256) void prep_kernel(
    const void* __restrict__ h, const void* __restrict__ Wi,
    const void* __restrict__ Wj, const void* __restrict__ ai,
    const void* __restrict__ aj, const void* __restrict__ ab,
    u16* __restrict__ Bt, float* __restrict__ v,
    float* __restrict__ ajf, float* __restrict__ abf) {
  __shared__ u16 tile[64][65];
  const int f32m = detect_f32((const u32*)h);
  const int bid = blockIdx.x, tid = threadIdx.x;
  if (bid < 60) {                                  // transpose: 10(f) x 6(h) tiles
    const int ft = bid / 6, ht = bid - ft * 6;
    const int f0 = ft * 64, h0 = ht * 64;
    const int ln = tid & 63, fg = tid >> 6;
#pragma unroll
    for (int rr = 0; rr < 16; ++rr) {
      const int fl = fg * 16 + rr;
      const int f = f0 + fl;
      if (f < INF_)
        tile[fl][ln] = f32m ? f2bf(((const float*)Wj)[(size_t)f * HID_ + h0 + ln])
                            : ((const u16*)Wj)[(size_t)f * HID_ + h0 + ln];
    }
    __syncthreads();
#pragma unroll
    for (int rr = 0; rr < 16; ++rr) {
      const int hl = fg * 16 + rr;
      const int f = f0 + ln;
      if (f < INF_) Bt[(size_t)(h0 + hl) * INF_ + f] = tile[ln][hl];
    }
  } else if (bid < 98) {                           // v: 16-lane group per row
    const int t = (bid - 60) * 16 + (tid >> 4);
    const int sl = tid & 15;
    if (t < INF_) {
      float s = 0.f;
      if (f32m) {
        const float4* wi = (const float4*)((const float*)Wi + (size_t)t * HID_);
        const float4* a4 = (const float4*)ai;
        for (int c = sl; c < 96; c += 16) {
          float4 x = wi[c], y = a4[c];
          s += x.x * y.x + x.y * y.y + x.z * y.z + x.w * y.w;
        }
      } else {
        const uint4* wi = (const uint4*)((const u16*)Wi + (size_t)t * HID_);
        const uint4* a4 = (const uint4*)ai;
        for (int c = sl; c < 48; c += 16) {
          uint4 x = wi[c], y = a4[c];
          s += bflo(x.x) * bflo(y.x) + bfhi(x.x) * bfhi(y.x)
             + bflo(x.y) * bflo(y.y) + bfhi(x.y) * bfhi(y.y)
             + bflo(x.z) * bflo(y.z) + bfhi(x.z) * bfhi(y.z)
             + bflo(x.w) * bflo(y.w) + bfhi(x.w) * bfhi(y.w);
        }
      }
      s += __shfl_xor(s, 1); s += __shfl_xor(s, 2);
      s += __shfl_xor(s, 4); s += __shfl_xor(s, 8);
      if (sl == 0) v[t] = s;
    }
  } else {                                         // ajf/abf only
    for (int j = tid; j < HID_; j += 256)
      ajf[j] = f32m ? ((const float*)aj)[j] : bfu(((const u16*)aj)[j]);
    if (tid == 0)
      abf[0] = f32m ? ((const float*)ab)[0] : bfu(((const u16*)ab)[0]);
  }
}

// ---- gemm_fused: r0 structure (512 blk x 256 thr, BM=32, known 43.6us) with
// ONE counter-backed fix: Bs 8-way LDS bank conflict (SQ_LDS_BANK_CONFLICT
// 1.09M, r1) killed by a both-sides XOR swizzle (rule 21): LDS dest stays
// linear; the GLOBAL source piece index is permuted p = s ^ ((r+(r>>2))&3)
// at staging, and the ds_read applies the same XOR -> 2-way (free, m136).
// Also sj via LDS cross-wave reduce (r1-validated) instead of atomics. ----
__global__ __launch_bounds__(256) void gemm_fused(
    const void* __restrict__ A, const u16* __restrict__ Bt,
    const float* __restrict__ v, u16* __restrict__ C,
    float* __restrict__ si, const float* __restrict__ ajf,
    float* __restrict__ sj) {
  __shared__ __align__(16) u16 As[32][612];
  __shared__ __align__(16) u16 Bs[12288];          // [384][32], piece-swizzled
  const int f32m = detect_f32((const u32*)A);
  const int tid  = threadIdx.x;
  const int lane = tid & 63;
  const int wv   = tid >> 6;
  const int row0 = blockIdx.x * 32;
  const char* Btb = (const char*)Bt;

#pragma unroll
  for (int i = 0; i < 6; ++i) {
    const int c = tid + i * 256;
    const int r = c >> 2;
    const int p = (c & 3) ^ ((r + (r >> 2)) & 3);  // inverse-swizzled source
    async_ld16(Btb + (size_t)r * 1216 + p * 16, (char*)Bs + c * 16);
  }

  {
    const int g = tid >> 3, sub = tid & 7;
    float s = 0.f;
    const float4* v4 = (const float4*)v;
    if (f32m) {
      const float4* hr = (const float4*)((const float*)A + (size_t)(row0 + g) * INF_);
#pragma unroll
      for (int k = 0; k < 19; ++k) {
        const int c4 = sub + 8 * k;
        float4 x = hr[c4];
        ushort4 sv;
        sv.x = f2bf(x.x); sv.y = f2bf(x.y); sv.z = f2bf(x.z); sv.w = f2bf(x.w);
        *(ushort4*)&As[g][c4 * 4] = sv;
        float4 w = v4[c4];
        s += x.x * w.x + x.y * w.y + x.z * w.z + x.w * w.w;
      }
    } else {
      const uint4* hr = (const uint4*)((const u16*)A + (size_t)(row0 + g) * INF_);
      for (int k = 0; k < 10; ++k) {
        const int c8 = sub + 8 * k;
        if (c8 < 76) {
          uint4 x = hr[c8];
          *(ushort4*)&As[g][c8 * 8]     = *(ushort4*)&x.x;
          *(ushort4*)&As[g][c8 * 8 + 4] = *(ushort4*)&x.z;
          float4 w0 = v4[2 * c8], w1 = v4[2 * c8 + 1];
          s += bflo(x.x) * w0.x + bfhi(x.x) * w0.y + bflo(x.y) * w0.z + bfhi(x.y) * w0.w
             + bflo(x.z) * w1.x + bfhi(x.z) * w1.y + bflo(x.w) * w1.z + bfhi(x.w) * w1.w;
        }
      }
    }
    s += __shfl_xor(s, 1); s += __shfl_xor(s, 2); s += __shfl_xor(s, 4);
    if (sub == 0) si[row0 + g] = s;
  }

  f32x4 acc[2][6];
#pragma unroll
  for (int i = 0; i < 2; ++i)
#pragma unroll
    for (int j = 0; j < 6; ++j) acc[i][j] = (f32x4){0.f, 0.f, 0.f, 0.f};

  const int lm = lane & 15, q = lane >> 4;
  const int n0 = wv * 96;
  const int tr = (lm + (lm >> 2)) & 3;             // == (r + (r>>2))&3 for
                                                   // r = n0+in*16+lm (n0,16in ≡ 0 mod 4 after >>2 fold)
  for (int kt = 0; kt < 19; ++kt) {
    __syncthreads();
    bf16x8 af[2], bfr[6];
#pragma unroll
    for (int im = 0; im < 2; ++im) {
      const int r = im * 16 + lm;
      bf16x4 lo = *(const bf16x4*)&As[r][kt * 32 + q * 8];
      bf16x4 hi = *(const bf16x4*)&As[r][kt * 32 + q * 8 + 4];
      af[im] = __builtin_shufflevector(lo, hi, 0, 1, 2, 3, 4, 5, 6, 7);
    }
#pragma unroll
    for (int in = 0; in < 6; ++in)
      bfr[in] = *(const bf16x8*)&Bs[(n0 + in * 16 + lm) * 32 + ((q ^ tr) * 8)];
#pragma unroll
    for (int im = 0; im < 2; ++im)
#pragma unroll
      for (int in = 0; in < 6; ++in)
        acc[im][in] = __builtin_amdgcn_mfma_f32_16x16x32_bf16(
            af[im], bfr[in], acc[im][in], 0, 0, 0);
    __syncthreads();
    if (kt < 18) {
      const size_t kb = (size_t)(kt + 1) * 64;
#pragma unroll
      for (int i = 0; i < 6; ++i) {
        const int c = tid + i * 256;
        const int r = c >> 2;
        const int p = (c & 3) ^ ((r + (r >> 2)) & 3);
        async_ld16(Btb + (size_t)r * 1216 + kb + p * 16, (char*)Bs + c * 16);
      }
    }
  }

#pragma unroll
  for (int im = 0; im < 2; ++im)
#pragma unroll
    for (int in = 0; in < 6; ++in) {
      const int colg = n0 + in * 16 + lm;
#pragma unroll
      for (int r = 0; r < 4; ++r) {
        const int rowg = row0 + im * 16 + q * 4 + r;
        C[(size_t)rowg * HID_ + colg] = f2bf(acc[im][in][r]);
      }
    }
  // sj: per-wave shfl reduce -> LDS (Bs dead after last barrier+reads) ->
  // cross-wave sum, plain store (block owns its 32 rows exclusively).
  float* sjred = (float*)Bs;                       // [4][32] f32 = 512 B
  float ajv[6];
#pragma unroll
  for (int in = 0; in < 6; ++in) ajv[in] = ajf[n0 + in * 16 + lm];
#pragma unroll
  for (int im = 0; im < 2; ++im)
#pragma unroll
    for (int r = 0; r < 4; ++r) {
      float p = acc[im][0][r] * ajv[0] + acc[im][1][r] * ajv[1]
              + acc[im][2][r] * ajv[2] + acc[im][3][r] * ajv[3]
              + acc[im][4][r] * ajv[4] + acc[im][5][r] * ajv[5];
      p += __shfl_xor(p, 1); p += __shfl_xor(p, 2);
      p += __shfl_xor(p, 4); p += __shfl_xor(p, 8);
      if (lm == 0) sjred[wv * 32 + im * 16 + q * 4 + r] = p;
    }
  __syncthreads();
  if (tid < 32)
    sj[row0 + tid] = sjred[tid] + sjred[32 + tid] + sjred[64 + tid] + sjred[96 + tid];
}

// ---- attn: r0 version EXACTLY (best measured: 43.7us). 5 rows/block,
// ballot-compacted valid-k gather, 8-deep batching, 3277 x 256. ----
__global__ __launch_bounds__(256) void attn_kernel(
    const void* __restrict__ h, const int* __restrict__ ci,
    const float* __restrict__ si, const float* __restrict__ sj,
    const float* __restrict__ abf, const u16* __restrict__ Wh,
    void* __restrict__ out) {
  __shared__ float2 ai_c[5][32];     // .x = att weight, .y = idx bits
  __shared__ int cnt_s[5];
  const int f32m = detect_f32((const u32*)h);
  const int i64  = detect_i64(ci);
  const int tid = threadIdx.x;
  const int n0 = blockIdx.x * 5;

  if (tid < 160) {
    const int r = tid >> 5, k = tid & 31;
    const int n = n0 + r;
    if (n < NBOX) {
      const size_t t = (size_t)n * KCTX + k;
      int idx;
      if (i64) { int lo = ci[2 * t], hi2 = ci[2 * t + 1]; idx = (hi2 < 0) ? -1 : lo; }
      else     { idx = ci[t]; }
      const bool valid = idx >= 0;
      const float sjv = valid ? sj[idx] : 0.f;
      float raw = si[n] + sjv + abf[0];
      float lr = raw > 0.f ? raw : 0.2f * raw;
      float s = valid ? lr : -9e15f;
      float m = s;
#pragma unroll
      for (int o = 16; o; o >>= 1) m = fmaxf(m, __shfl_xor(m, o, 32));
      float p = __expf(s - m);
      float d = p;
#pragma unroll
      for (int o = 16; o; o >>= 1) d += __shfl_xor(d, o, 32);
      // compact valid entries to the front of ai_c[r]
      const unsigned long long bm = __ballot(valid);
      const u32 m32 = (u32)(bm >> (tid & 32));     // this 32-group's mask
      const int cnt = __popc(m32);
      const int r8 = (cnt + 7) & ~7;               // pad to multiple of 8
      if (valid) {
        const int pf = __popc(m32 & ((1u << k) - 1u));
        ai_c[r][pf] = (float2){p / d, __int_as_float(idx)};
      }
      if (k >= cnt && k < r8) ai_c[r][k] = (float2){0.f, 0.f};  // pad: w=0, idx=0
      if (k == 0) cnt_s[r] = r8;
    } else if ((tid & 31) == 0) {
      cnt_s[r] = 0;
    }
  }
  __syncthreads();

  if (tid < 240) {
    const int r = tid / 48, c = tid - r * 48;
    const int n = n0 + r;
    if (n < NBOX) {
      const int K8 = cnt_s[r];
      float a0 = 0, a1 = 0, a2 = 0, a3 = 0, a4 = 0, a5 = 0, a6 = 0, a7 = 0;
      for (int kb = 0; kb < K8; kb += 8) {
        uint4 q[8]; float ww[8];
#pragma unroll
        for (int u = 0; u < 8; ++u) {              // 8 loads in flight
          const float2 e = ai_c[r][kb + u];
          ww[u] = e.x;
          const int j = __float_as_int(e.y);
          q[u] = ((const uint4*)(Wh + (u32)j * HID_))[c];
        }
#pragma unroll
        for (int u = 0; u < 8; ++u) {
          const float w = ww[u];
          a0 += w * bflo(q[u].x); a1 += w * bfhi(q[u].x);
          a2 += w * bflo(q[u].y); a3 += w * bfhi(q[u].y);
          a4 += w * bflo(q[u].z); a5 += w * bfhi(q[u].z);
          a6 += w * bflo(q[u].w); a7 += w * bfhi(q[u].w);
        }
      }
      if (f32m) {
        float4* o4 = (float4*)out + (size_t)n * 96 + c * 2;
        o4[0] = (float4){a0, a1, a2, a3};
        o4[1] = (float4){a4, a5, a6, a7};
      } else {
        uint4 o;
        o.x = (u32)f2bf(a0) | ((u32)f2bf(a1) << 16);
        o.y = (u32)f2bf(a2) | ((u32)f2bf(a3) << 16);
        o.z = (u32)f2bf(a4) | ((u32)f2bf(a5) << 16);
        o.w = (u32)f2bf(a6) | ((u32)f2bf(a7) << 16);
        ((uint4*)out)[(size_t)n * 48 + c] = o;
      }
    }
  }
}

extern "C" void kernel_launch(void* const* d_in, const int* in_sizes, int n_in,
                              void* d_out, int out_size, void* d_ws, size_t ws_size,
                              hipStream_t stream) {
  const void* h  = d_in[0];
  const int*  ci = (const int*)d_in[1];
  const void* Wi = d_in[2];
  const void* Wj = d_in[3];
  const void* ai = d_in[4];
  const void* aj = d_in[5];
  const void* ab = d_in[6];

  char* ws = (char*)d_ws;
  u16*   Wh  = (u16*)(ws + WH_OFF);
  u16*   Bt  = (u16*)(ws + BT_OFF);
  float* v   = (float*)(ws + V_OFF);
  float* si  = (float*)(ws + SI_OFF);
  float* sj  = (float*)(ws + SJ_OFF);
  float* ajf = (float*)(ws + AJF_OFF);
  float* abf = (float*)(ws + ABF_OFF);

  prep_kernel<<<99, 256, 0, stream>>>(h, Wi, Wj, ai, aj, ab, Bt, v, ajf, abf);
  gemm_fused<<<512, 256, 0, stream>>>(h, Bt, v, Wh, si, ajf, sj);
  attn_kernel<<<3277, 256, 0, stream>>>(h, ci, si, sj, abf, Wh, d_out);
}